// Round 11
// baseline (136.181 us; speedup 1.0000x reference)
//
#include <hip/hip_runtime.h>
#include <stdint.h>

typedef _Float16 half8 __attribute__((ext_vector_type(8)));
typedef _Float16 half4 __attribute__((ext_vector_type(4)));
typedef __fp16   fp16x2 __attribute__((ext_vector_type(2)));
typedef float    floatx4 __attribute__((ext_vector_type(4)));

#define T_LEN 2048
#define CH 64
#define BH 32            // bs * n_heads
#define QTILE 128        // t per block (32 per wave-pair slot)
#define LDP 72           // prep LDS pad (halves)
#define PTP 72           // Pt row stride (halves)
#define FRAG_BH 131072   // halves per bh per tensor (64*2048)

// ---------------- pass 1: fp32 -> fp16, reorder into MFMA fragment order ----------
// Q pre-scaled by 0.125 * rescale * log2(e) so attention does raw exp2.
// QF/KF[bh][g][ks][lane][8]: g = t(or s)>>4, element = X[c = ks*32+quad*8+j][t = g*16+l15]
// VF[bh][stile64][ct*2+ks][lane][8]: element = V[c = ct*16+l15][s = stile64*64+ks*32+quad*8+j]
__global__ __launch_bounds__(256, 2)
void prep_kernel(const float* __restrict__ qkv, const float* __restrict__ rescale,
                 _Float16* __restrict__ ws)
{
    __shared__ _Float16 Qs[64][LDP];   // [t][c]
    __shared__ _Float16 Ks[64][LDP];   // [s][c]
    __shared__ _Float16 Vs[64][LDP];   // [c][s]

    const int tid  = threadIdx.x;
    const int bh   = blockIdx.y;
    const int tile = blockIdx.x;       // 64-element tile along t/s
    const int x0   = tile * 64;

    const float qscale = 0.125f * 1.4426950408889634f * rescale[0];

    const float* qp = qkv + (size_t)(bh >> 3) * (1536 * T_LEN)
                          + (size_t)(bh & 7) * (192 * T_LEN);
    const float* kp = qp + 64 * T_LEN;
    const float* vp = qp + 128 * T_LEN;

    // Q,K: 4x4 register-block transpose [c][t] -> [t][c]
    {
        const int a4 = (tid & 15) * 4;
        const int c4 = (tid >> 4) * 4;
        float4 rq[4], rk[4];
#pragma unroll
        for (int i = 0; i < 4; ++i) {
            rq[i] = *(const float4*)(qp + (size_t)(c4 + i) * T_LEN + x0 + a4);
            rk[i] = *(const float4*)(kp + (size_t)(c4 + i) * T_LEN + x0 + a4);
        }
#pragma unroll
        for (int j = 0; j < 4; ++j) {
            half4 hq, hk;
#pragma unroll
            for (int i = 0; i < 4; ++i) {
                hq[i] = (_Float16)((&rq[i].x)[j] * qscale);
                hk[i] = (_Float16)((&rk[i].x)[j]);
            }
            *(half4*)&Qs[a4 + j][c4] = hq;
            *(half4*)&Ks[a4 + j][c4] = hk;
        }
        // V natural [c][s]
        const int s4 = (tid & 15) * 4;
        const int cv = tid >> 4;
#pragma unroll
        for (int i = 0; i < 4; ++i) {
            const int c = cv + 16 * i;
            float4 r = *(const float4*)(vp + (size_t)c * T_LEN + x0 + s4);
            half4 h; h[0]=(_Float16)r.x; h[1]=(_Float16)r.y; h[2]=(_Float16)r.z; h[3]=(_Float16)r.w;
            *(half4*)&Vs[c][s4] = h;
        }
    }
    __syncthreads();

    const int lane = tid & 63, wave = tid >> 6;
    const int l15 = lane & 15, quad = lane >> 4;
    _Float16* qf = ws;
    _Float16* kf = ws + (size_t)BH * FRAG_BH;
    _Float16* vf = ws + (size_t)2 * BH * FRAG_BH;

#pragma unroll
    for (int ks = 0; ks < 2; ++ks) {
        half8 hq = *(const half8*)&Qs[wave * 16 + l15][ks * 32 + quad * 8];
        half8 hk = *(const half8*)&Ks[wave * 16 + l15][ks * 32 + quad * 8];
        half8 hv = *(const half8*)&Vs[wave * 16 + l15][ks * 32 + quad * 8];
        const size_t gqk = (((size_t)bh * 128 + tile * 4 + wave) * 2 + ks) * 512 + lane * 8;
        *(half8*)(qf + gqk) = hq;
        *(half8*)(kf + gqk) = hk;
        *(half8*)(vf + (((size_t)bh * 32 + tile) * 8 + wave * 2 + ks) * 512 + lane * 8) = hv;
    }
}

// ---------------- pass 2: attention, s-split, barrier-free main loop ---------------
// 512-thread blocks, 8 waves: waves 0-3 do s-tiles [0,16), waves 4-7 do [16,32) for
// the SAME 128 queries -> per-block K/V traffic unchanged vs R10 but 2x the waves
// (4/SIMD), halving per-wave chain depth. Main loop identical to R10 (register
// pipelining, per-wave Pt LDS round-trip, no barriers). One barrier total: the
// post-loop partial combine O=(O_lo+O_hi)/(l_lo+l_hi) through LDS.
__global__ __launch_bounds__(512, 4)
void attn_kernel(const _Float16* __restrict__ ws, float* __restrict__ out)
{
    __shared__ _Float16 Pt[8][32][PTP];      // per wave: [t_rel 32][s_rel 64]  36.9 KB
    __shared__ float    Obuf[4][2][4][64][4]; // [pair][tb][ct][lane][r]        32 KB
    __shared__ float    Lbuf[4][2][4][4];     // [pair][tb][quad][r]            0.5 KB

    const int tid  = threadIdx.x;
    const int wave = tid >> 6;
    const int lane = tid & 63;
    const int l15  = lane & 15;
    const int quad = lane >> 4;
    const int wlocal = wave & 3;     // t-slot within block
    const int sgrp   = wave >> 2;    // 0: s [0,1024), 1: s [1024,2048)

    const int bh = blockIdx.y;
    const int t0 = blockIdx.x * QTILE;

    const _Float16* qf = ws;
    const _Float16* kf = ws + (size_t)BH * FRAG_BH;
    const _Float16* vf = ws + (size_t)2 * BH * FRAG_BH;
    float* op = out + (size_t)bh * (CH * T_LEN);

    const _Float16* kfp = kf + (size_t)bh * FRAG_BH + (size_t)sgrp * 16 * 4096 + lane * 8;
    const _Float16* vfp = vf + (size_t)bh * FRAG_BH + (size_t)sgrp * 16 * 4096 + lane * 8;

    // Q fragments: persistent (Q pre-scaled in prep); 32 t per wave = 2 t-groups
    half8 bq[2][2];
#pragma unroll
    for (int tb = 0; tb < 2; ++tb)
#pragma unroll
        for (int ks = 0; ks < 2; ++ks)
            bq[tb][ks] = *(const half8*)(qf +
                (((size_t)bh * 128 + blockIdx.x * 8 + wlocal * 2 + tb) * 2 + ks) * 512 + lane * 8);

    const floatx4 fzero = {0.f, 0.f, 0.f, 0.f};
    floatx4 oacc[2][4];                 // [tb][ctile]
#pragma unroll
    for (int tb = 0; tb < 2; ++tb)
#pragma unroll
        for (int ct = 0; ct < 4; ++ct) oacc[tb][ct] = fzero;
    floatx4 lacc[2] = {fzero, fzero};   // row sums via ones-MFMA

    half8 bones;
#pragma unroll
    for (int i = 0; i < 8; ++i) bones[i] = (_Float16)1.0f;

    half8 ak[4][2];    // K(st): loaded one iteration ahead of its QK
    half8 bv[4][2];    // V(st-1) at loop top
    half8 ap[2][2];    // P(st-1) at loop top

    // QK + exp + Pt round-trip for current ak
    auto do_qk_exp = [&]() {
        floatx4 sacc[4][2];
#pragma unroll
        for (int mt = 0; mt < 4; ++mt)
#pragma unroll
            for (int tb = 0; tb < 2; ++tb) sacc[mt][tb] = fzero;
#pragma unroll
        for (int mt = 0; mt < 4; ++mt)
#pragma unroll
            for (int tb = 0; tb < 2; ++tb)
#pragma unroll
                for (int ks = 0; ks < 2; ++ks)
                    sacc[mt][tb] = __builtin_amdgcn_mfma_f32_16x16x32_f16(
                        ak[mt][ks], bq[tb][ks], sacc[mt][tb], 0, 0, 0);

        // p = exp2(logit), packed f32->f16; lane owns t=l15, s = mt*16+quad*4+r
#pragma unroll
        for (int mt = 0; mt < 4; ++mt)
#pragma unroll
            for (int tb = 0; tb < 2; ++tb) {
                fp16x2 p01 = __builtin_amdgcn_cvt_pkrtz(
                    __builtin_amdgcn_exp2f(sacc[mt][tb][0]),
                    __builtin_amdgcn_exp2f(sacc[mt][tb][1]));
                fp16x2 p23 = __builtin_amdgcn_cvt_pkrtz(
                    __builtin_amdgcn_exp2f(sacc[mt][tb][2]),
                    __builtin_amdgcn_exp2f(sacc[mt][tb][3]));
                half4 ph;
                ph[0] = (_Float16)p01[0]; ph[1] = (_Float16)p01[1];
                ph[2] = (_Float16)p23[0]; ph[3] = (_Float16)p23[1];
                *(half4*)&Pt[wave][tb * 16 + l15][mt * 16 + quad * 4] = ph;
            }
        // ap read issued now; per-wave DS in-order => sees the writes above;
        // latency spans into the next iteration's PV.
#pragma unroll
        for (int tb = 0; tb < 2; ++tb)
#pragma unroll
            for (int ks = 0; ks < 2; ++ks)
                ap[tb][ks] = *(const half8*)&Pt[wave][tb * 16 + l15][ks * 32 + quad * 8];
    };

    // ---- prologue: local tile 0
#pragma unroll
    for (int mt = 0; mt < 4; ++mt)
#pragma unroll
        for (int ks = 0; ks < 2; ++ks)
            ak[mt][ks] = *(const half8*)(kfp + (size_t)(mt * 2 + ks) * 512);
#pragma unroll
    for (int ct = 0; ct < 4; ++ct)
#pragma unroll
        for (int ks = 0; ks < 2; ++ks)
            bv[ct][ks] = *(const half8*)(vfp + (size_t)(ct * 2 + ks) * 512);
    do_qk_exp();
    // K(1) issued now (full iteration to land)
#pragma unroll
    for (int mt = 0; mt < 4; ++mt)
#pragma unroll
        for (int ks = 0; ks < 2; ++ks)
            ak[mt][ks] = *(const half8*)(kfp + 4096 + (size_t)(mt * 2 + ks) * 512);

    // ---- main loop: 16 local tiles per wave
#pragma unroll 2
    for (int st = 1; st < 16; ++st) {
        // PV(st-1): operands resolved; independent MFMA work at iteration top
#pragma unroll
        for (int tb = 0; tb < 2; ++tb)
#pragma unroll
            for (int ks = 0; ks < 2; ++ks)
                lacc[tb] = __builtin_amdgcn_mfma_f32_16x16x32_f16(ap[tb][ks], bones, lacc[tb], 0, 0, 0);
#pragma unroll
        for (int tb = 0; tb < 2; ++tb)
#pragma unroll
            for (int ct = 0; ct < 4; ++ct)
#pragma unroll
                for (int ks = 0; ks < 2; ++ks)
                    oacc[tb][ct] = __builtin_amdgcn_mfma_f32_16x16x32_f16(
                        ap[tb][ks], bv[ct][ks], oacc[tb][ct], 0, 0, 0);

        // V(st): issue now, consumed at next iteration's PV
        const _Float16* vcur = vfp + (size_t)st * 4096;
#pragma unroll
        for (int ct = 0; ct < 4; ++ct)
#pragma unroll
            for (int ks = 0; ks < 2; ++ks)
                bv[ct][ks] = *(const half8*)(vcur + (size_t)(ct * 2 + ks) * 512);

        // QK(st) with ak (issued one iteration ago), then exp -> Pt -> ap
        do_qk_exp();

        // K(st+1): issue now, consumed at next iteration's QK
        if (st < 15) {
            const _Float16* kcur = kfp + (size_t)(st + 1) * 4096;
#pragma unroll
            for (int mt = 0; mt < 4; ++mt)
#pragma unroll
                for (int ks = 0; ks < 2; ++ks)
                    ak[mt][ks] = *(const half8*)(kcur + (size_t)(mt * 2 + ks) * 512);
        }
    }

    // ---- epilogue: PV(15)
#pragma unroll
    for (int tb = 0; tb < 2; ++tb)
#pragma unroll
        for (int ks = 0; ks < 2; ++ks)
            lacc[tb] = __builtin_amdgcn_mfma_f32_16x16x32_f16(ap[tb][ks], bones, lacc[tb], 0, 0, 0);
#pragma unroll
    for (int tb = 0; tb < 2; ++tb)
#pragma unroll
        for (int ct = 0; ct < 4; ++ct)
#pragma unroll
            for (int ks = 0; ks < 2; ++ks)
                oacc[tb][ct] = __builtin_amdgcn_mfma_f32_16x16x32_f16(
                    ap[tb][ks], bv[ct][ks], oacc[tb][ct], 0, 0, 0);

    // ---- combine halves: upper quad publishes partials, lower quad reduces+stores
    if (sgrp == 1) {
#pragma unroll
        for (int tb = 0; tb < 2; ++tb) {
#pragma unroll
            for (int ct = 0; ct < 4; ++ct)
                *(floatx4*)&Obuf[wlocal][tb][ct][lane][0] = oacc[tb][ct];
            if (l15 == 0)
                *(floatx4*)&Lbuf[wlocal][tb][quad][0] = lacc[tb];
        }
    }
    __syncthreads();
    if (sgrp == 0) {
#pragma unroll
        for (int tb = 0; tb < 2; ++tb) {
            floatx4 lhi = *(const floatx4*)&Lbuf[wlocal][tb][quad][0];  // quad-broadcast
            float linv[4];
#pragma unroll
            for (int r = 0; r < 4; ++r) linv[r] = 1.0f / (lacc[tb][r] + lhi[r]);
#pragma unroll
            for (int ct = 0; ct < 4; ++ct) {
                floatx4 ohi = *(const floatx4*)&Obuf[wlocal][tb][ct][lane][0];
                const int c = ct * 16 + l15;
                const int t = t0 + wlocal * 32 + tb * 16 + quad * 4;
                float4 o;
#pragma unroll
                for (int r = 0; r < 4; ++r)
                    (&o.x)[r] = (oacc[tb][ct][r] + ohi[r]) * linv[r];
                *(float4*)(op + (size_t)c * T_LEN + t) = o;
            }
        }
    }
}

extern "C" void kernel_launch(void* const* d_in, const int* in_sizes, int n_in,
                              void* d_out, int out_size, void* d_ws, size_t ws_size,
                              hipStream_t stream) {
    const float* qkv     = (const float*)d_in[0];
    const float* rescale = (const float*)d_in[1];
    float* out = (float*)d_out;
    _Float16* ws = (_Float16*)d_ws;   // needs 3*32*131072*2 B = 25.2 MB

    prep_kernel<<<dim3(32, BH), dim3(256), 0, stream>>>(qkv, rescale, ws);
    attn_kernel<<<dim3(T_LEN / QTILE, BH), dim3(512), 0, stream>>>(ws, out);
}